// Round 4
// baseline (469.553 us; speedup 1.0000x reference)
//
#include <hip/hip_runtime.h>

// Fuzzy c-means on MI355X. N=300000, D=64, c=64, m=2 (p=2), 25 updates + init.
// R4: MFMA rewrite (432us). R5: bf16 xbf copy (427us). R6: VALU cuts (401us).
// R7: coalesced prep, nb=768 (390us). R8: per-wave-points GEMM1 (388us) --
// under-delivered => pass is latency/barrier-bound, not VALU-bound.
// R9: (a) pass pipelined: double-buffered Xb/XTb/x2s, GEMM2 deferred one tile,
//     next tile's xbf loads issued a full tile early -> 2 barriers/tile and
//     global latency off the critical path. (b) reduce 64x1024 -> 256x256
//     (4 blocks per j) with atomic accumulator + per-j ticket finalize.

#define DM 64
#define CL 64
#define PARTIAL_STRIDE 4160      // 64*64 num + 64 den
#define MAX_ITER 25
#define MAX_BLOCKS 768
#define LDP 72                   // padded row length (bf16) for Xb/XTb/umT
#define ZACC_SZ 4224             // Cacc 4096 + Dacc 64 + jtick 64

typedef __attribute__((ext_vector_type(8))) short bf16x8;   // MFMA A/B frag (4 VGPRs)
typedef __attribute__((ext_vector_type(4))) float f32x4;    // MFMA C/D frag

__device__ __forceinline__ unsigned f2bf1(float f) {        // fp32 -> bf16 (RNE)
  unsigned u = __builtin_bit_cast(unsigned, f);
  return (u + 0x7FFFu + ((u >> 16) & 1u)) >> 16;
}
__device__ __forceinline__ unsigned pkbf(float a, float b) {
  return f2bf1(a) | (f2bf1(b) << 16);
}
// HW packed fp32->2xbf16 (RNE), gfx950. %1 -> low half, %2 -> high half.
__device__ __forceinline__ unsigned cvtpk_bf16(float a, float b) {
  unsigned r;
  asm("v_cvt_pk_bf16_f32 %0, %1, %2" : "=v"(r) : "v"(a), "v"(b));
  return r;
}

// 64-lane sum: DPP row reduce + bcast, result broadcast via readlane 63.
__device__ __forceinline__ float wave_sum(float v) {
#define DPPADD(ctrl, rmask)                                                  \
  v += __builtin_bit_cast(float, __builtin_amdgcn_update_dpp(                \
           0, __builtin_bit_cast(int, v), ctrl, rmask, 0xf, false));
  DPPADD(0x111, 0xf)   // row_shr:1
  DPPADD(0x112, 0xf)   // row_shr:2
  DPPADD(0x114, 0xf)   // row_shr:4
  DPPADD(0x118, 0xf)   // row_shr:8
  DPPADD(0x142, 0xa)   // row_bcast:15
  DPPADD(0x143, 0xc)   // row_bcast:31
#undef DPPADD
  return __builtin_bit_cast(
      float, __builtin_amdgcn_readlane(__builtin_bit_cast(int, v), 63));
}

// all-lanes sum within each 16-lane group, pure VALU (DPP).
__device__ __forceinline__ float group16_sum(float v) {
#define DPPADD(ctrl)                                                         \
  v += __builtin_bit_cast(float, __builtin_amdgcn_update_dpp(                \
           0, __builtin_bit_cast(int, v), ctrl, 0xf, 0xf, false));
  DPPADD(0xB1)    // quad_perm [1,0,3,2]  (xor 1)
  DPPADD(0x4E)    // quad_perm [2,3,0,1]  (xor 2)
  DPPADD(0x141)   // row_half_mirror
  DPPADD(0x140)   // row_mirror
#undef DPPADD
  return v;
}

// Coalesced prep: one float4 per lane, 16 lanes = one data row.
// Also zeroes the reduce accumulators (zacc) and the control flags.
__global__ __launch_bounds__(256)
void fcm_prep(const float* __restrict__ data, float* __restrict__ x2,
              unsigned short* __restrict__ xbf, float* __restrict__ zacc,
              float* __restrict__ diffac, int* __restrict__ done,
              int* __restrict__ ticket, int N) {
  size_t i = (size_t)blockIdx.x * blockDim.x + threadIdx.x;   // float4 index
  if (i == 0) { *diffac = 0.0f; *done = 0; *ticket = 0; }
  if (i < ZACC_SZ) zacc[i] = 0.0f;       // Cacc/Dacc/jtick
  size_t nvec = (size_t)N * (DM / 4);
  if (i >= nvec) return;                 // rows are 16 vecs: groups all-in/all-out
  float4 v = ((const float4*)data)[i];
  float s = fmaf(v.x, v.x, fmaf(v.y, v.y, fmaf(v.z, v.z, v.w * v.w)));
  float rs = group16_sum(s);             // row sum across the 16-lane group
  if ((threadIdx.x & 15) == 0) x2[i >> 4] = rs;
  uint2 pk = {cvtpk_bf16(v.x, v.y), cvtpk_bf16(v.z, v.w)};
  ((uint2*)xbf)[i] = pk;
}

// Fused pass, software-pipelined:
//   iter i: barA; [GEMM2(prev tile) || stage regs->buf c]; issue loads(i+1);
//           barB; GEMM1+softmax+umT(buf c).  Final GEMM2 drained after loop.
template <bool INIT>
__global__ __launch_bounds__(256, 3)
void fcm_pass(const unsigned short* __restrict__ xbf, const float* __restrict__ x2,
              const float* __restrict__ CU,   // INIT: u0[N][64]; else C[64][64]
              float* __restrict__ partial, const int* __restrict__ done,
              int N, int ntiles) {
  if (!INIT && *done) return;
  __shared__ __align__(16) unsigned short Xb[2][64 * LDP];   // X[p][d] bf16
  __shared__ __align__(16) unsigned short XTb[2][64 * LDP];  // X^T[d][p] bf16
  __shared__ __align__(16) unsigned short umT[64 * LDP];     // um^T[j][p] bf16
  __shared__ __align__(16) float x2s[2][64];

  const int tid  = threadIdx.x;
  const int w    = __builtin_amdgcn_readfirstlane(tid >> 6);  // wave id: POINT tile
  const int col  = tid & 15;
  const int quad = (tid >> 4) & 3;

  // ---- per-kernel prep: ALL 4 j-tiles' C rows -> c2v[jt] + bf16 B-frags ----
  bf16x8 cf0[4], cf1[4];
  float c2v[4];
  if (!INIT) {
#pragma unroll
    for (int jt = 0; jt < 4; jt++) {
      const float* crow = CU + (size_t)(16 * jt + col) * DM;
      float4 ca = *(const float4*)(crow + quad * 8);
      float4 cb = *(const float4*)(crow + quad * 8 + 4);
      float4 cc = *(const float4*)(crow + 32 + quad * 8);
      float4 cd = *(const float4*)(crow + 32 + quad * 8 + 4);
      float cp = ca.x*ca.x + ca.y*ca.y + ca.z*ca.z + ca.w*ca.w
               + cb.x*cb.x + cb.y*cb.y + cb.z*cb.z + cb.w*cb.w
               + cc.x*cc.x + cc.y*cc.y + cc.z*cc.z + cc.w*cc.w
               + cd.x*cd.x + cd.y*cd.y + cd.z*cd.z + cd.w*cd.w;
      cp += __shfl_xor(cp, 16, 64);
      cp += __shfl_xor(cp, 32, 64);
      c2v[jt] = cp;
      union { bf16x8 v; unsigned u[4]; } P0, P1;
      P0.u[0] = pkbf(ca.x, ca.y); P0.u[1] = pkbf(ca.z, ca.w);
      P0.u[2] = pkbf(cb.x, cb.y); P0.u[3] = pkbf(cb.z, cb.w);
      P1.u[0] = pkbf(cc.x, cc.y); P1.u[1] = pkbf(cc.z, cc.w);
      P1.u[2] = pkbf(cd.x, cd.y); P1.u[3] = pkbf(cd.z, cd.w);
      cf0[jt] = P0.v; cf1[jt] = P1.v;
    }
  }

  union { bf16x8 v; unsigned u[4]; } ON;
  ON.u[0] = ON.u[1] = ON.u[2] = ON.u[3] = 0x3F803F80u;   // bf16 1.0 x2
  const bf16x8 onesf = ON.v;

  f32x4 D2[4];
#pragma unroll
  for (int dt = 0; dt < 4; dt++) D2[dt] = f32x4{0.f, 0.f, 0.f, 0.f};
  f32x4 Dden = f32x4{0.f, 0.f, 0.f, 0.f};

  const int sp  = tid & 63;
  const int sd0 = (tid >> 6) * 8;                         // 0/8/16/24 by wave
  const unsigned short* gsrc = xbf + (size_t)sp * DM + sd0;

  // deferred GEMM2 over buffer cb (reads umT + XTb[cb], accumulates D2/Dden)
  auto do_gemm2 = [&](int cb) {
#pragma unroll
    for (int pb = 0; pb < 2; pb++) {
      bf16x8 au = *(const bf16x8*)(const void*)&umT[(16 * w + col) * LDP + pb * 32 + quad * 8];
      Dden = __builtin_amdgcn_mfma_f32_16x16x32_bf16(au, onesf, Dden, 0, 0, 0);
#pragma unroll
      for (int dt = 0; dt < 4; dt++) {
        bf16x8 bx = *(const bf16x8*)(const void*)&XTb[cb][(dt * 16 + col) * LDP + pb * 32 + quad * 8];
        D2[dt] = __builtin_amdgcn_mfma_f32_16x16x32_bf16(au, bx, D2[dt], 0, 0, 0);
      }
    }
  };

  // ---- prologue prefetch: tile #0 for this block ----
  bf16x8 rv0 = {0, 0, 0, 0, 0, 0, 0, 0};
  bf16x8 rv1 = {0, 0, 0, 0, 0, 0, 0, 0};
  float rx2 = 0.0f;
  {
    int t0 = blockIdx.x;
    if (t0 < ntiles) {
      int base = t0 * 64;
      int np = min(64, N - base);
      if (sp < np) {
        const unsigned short* g = gsrc + (size_t)base * DM;
        rv0 = *(const bf16x8*)(g);
        rv1 = *(const bf16x8*)(g + 32);
      }
      if (tid < 64 && base + tid < N) rx2 = x2[base + tid];
    }
  }

  int c = 0;
  int it = 0;
  for (int t = blockIdx.x; t < ntiles; t += gridDim.x, ++it) {
    const int base = t * 64;
    const int np = min(64, N - base);
    __syncthreads();                       // barA: prev compute done everywhere

    if (it > 0) do_gemm2(c ^ 1);           // finish previous tile (other buffer)

    // ---- stage prefetched regs -> buf c ----
    *(bf16x8*)(void*)&Xb[c][sp * LDP + sd0] = rv0;
    *(bf16x8*)(void*)&Xb[c][sp * LDP + sd0 + 32] = rv1;
#pragma unroll
    for (int k = 0; k < 8; k++) XTb[c][(sd0 + k) * LDP + sp] = (unsigned short)rv0[k];
#pragma unroll
    for (int k = 0; k < 8; k++) XTb[c][(sd0 + 32 + k) * LDP + sp] = (unsigned short)rv1[k];
    if (tid < 64) x2s[c][tid] = rx2;

    // ---- issue next tile's global loads (consumed next iteration) ----
    {
      int tn = t + gridDim.x;
      rv0 = bf16x8{0, 0, 0, 0, 0, 0, 0, 0};
      rv1 = bf16x8{0, 0, 0, 0, 0, 0, 0, 0};
      rx2 = 0.0f;
      if (tn < ntiles) {
        int nbase = tn * 64;
        int nnp = min(64, N - nbase);
        if (sp < nnp) {
          const unsigned short* g = gsrc + (size_t)nbase * DM;
          rv0 = *(const bf16x8*)(g);
          rv1 = *(const bf16x8*)(g + 32);
        }
        if (tid < 64 && nbase + tid < N) rx2 = x2[nbase + tid];
      }
    }
    __syncthreads();                       // barB: stage(c) done, umT free

    // ---- W[jt][r] for p = 16w+quad*4+r, j = 16jt+col ----
    float Wv[4][4];
    if (INIT) {
#pragma unroll
      for (int jt = 0; jt < 4; jt++)
#pragma unroll
        for (int r = 0; r < 4; r++) {
          int pl = 16 * w + quad * 4 + r;
          Wv[jt][r] = (pl < np)
              ? CU[(size_t)(base + pl) * CL + 16 * jt + col] : 0.0f;
        }
    } else {
      bf16x8 a0 = *(const bf16x8*)(const void*)&Xb[c][(16 * w + col) * LDP + quad * 8];
      bf16x8 a1 = *(const bf16x8*)(const void*)&Xb[c][(16 * w + col) * LDP + 32 + quad * 8];
      f32x4 x2p = *(const f32x4*)(const void*)&x2s[c][16 * w + quad * 4];
#pragma unroll
      for (int jt = 0; jt < 4; jt++) {
        f32x4 s = f32x4{0.f, 0.f, 0.f, 0.f};
        s = __builtin_amdgcn_mfma_f32_16x16x32_bf16(a0, cf0[jt], s, 0, 0, 0);
        s = __builtin_amdgcn_mfma_f32_16x16x32_bf16(a1, cf1[jt], s, 0, 0, 0);
#pragma unroll
        for (int r = 0; r < 4; r++) {
          float dist = fmaxf(fmaf(-2.0f, s[r], x2p[r] + c2v[jt]), 0.0f);
          Wv[jt][r] = __builtin_amdgcn_rcpf(dist);   // d^(-p/2), p=2
        }
      }
    }

    // ---- rowsum in-register: in-lane over jt, DPP over col (bcast in group) ----
    float rr[4];
#pragma unroll
    for (int r = 0; r < 4; r++) {
      float rs = Wv[0][r] + Wv[1][r] + Wv[2][r] + Wv[3][r];
      rs = group16_sum(rs);
      int pl = 16 * w + quad * 4 + r;
      rr[r] = (pl < np) ? __builtin_amdgcn_rcpf(rs) : 0.0f;
    }

    // ---- um = (W * rr)^2 -> bf16 umT write (hw cvt_pk) ----
#pragma unroll
    for (int jt = 0; jt < 4; jt++) {
      float u0v = Wv[jt][0] * rr[0], u1v = Wv[jt][1] * rr[1];
      float u2v = Wv[jt][2] * rr[2], u3v = Wv[jt][3] * rr[3];
      uint2 pk = {cvtpk_bf16(u0v * u0v, u1v * u1v),
                  cvtpk_bf16(u2v * u2v, u3v * u3v)};
      *(uint2*)(void*)&umT[(16 * jt + col) * LDP + 16 * w + quad * 4] = pk;
    }
    c ^= 1;
  }

  // ---- drain: last tile's GEMM2 ----
  if (it > 0) {
    __syncthreads();
    do_gemm2(c ^ 1);
  }

  // ---- epilogue: write per-block partial (den from MFMA, col-duplicated) ----
  float* pbuf = partial + (size_t)blockIdx.x * PARTIAL_STRIDE;
  if (col == 0) {
    float4 dv = {Dden[0], Dden[1], Dden[2], Dden[3]};
    *(float4*)(void*)&pbuf[CL * DM + 16 * w + quad * 4] = dv;
  }
#pragma unroll
  for (int dt = 0; dt < 4; dt++)
#pragma unroll
    for (int r = 0; r < 4; r++)
      pbuf[(size_t)(16 * w + quad * 4 + r) * DM + dt * 16 + col] = D2[dt][r];
}

// 256 blocks: 4 per j (quarter-splits of the nb partials). Quarter sums go
// into Cacc/Dacc via atomicAdd; the 4th block per j (jtick) finalizes the row;
// the 64th finalizer (ticket) does the convergence check. Accumulators are
// reset in-kernel so the next iteration starts clean.
__global__ __launch_bounds__(256)
void fcm_reduce(const float* __restrict__ partial, float* __restrict__ Cnew,
                const float* __restrict__ Cold, float* __restrict__ out,
                float* __restrict__ Cacc, float* __restrict__ Dacc,
                int* __restrict__ jtick,
                float* __restrict__ diffac, int* __restrict__ done,
                int* __restrict__ ticket, int compute_diff, int nb) {
  if (compute_diff && *done) return;
  __shared__ float red[4][64];
  __shared__ int lastflag;
  __shared__ float sdv;
  const int tid = threadIdx.x;
  const int j = blockIdx.x >> 2;
  const int q = blockIdx.x & 3;
  const int nbq = nb >> 2;
  const int i0 = q * nbq;
  const int iend = (q == 3) ? nb : i0 + nbq;
  const int d = tid & 63;
  const int slice = tid >> 6;

  float s = 0.0f;
  for (int i = i0 + slice; i < iend; i += 4)
    s += partial[(size_t)i * PARTIAL_STRIDE + j * DM + d];
  red[slice][d] = s;
  __syncthreads();
  if (tid < 64) {
    float ss = red[0][d] + red[1][d] + red[2][d] + red[3][d];
    atomicAdd(&Cacc[j * DM + d], ss);
    float dv = 0.0f;
    for (int i = i0 + d; i < iend; i += 64)
      dv += partial[(size_t)i * PARTIAL_STRIDE + CL * DM + j];
    float dsum = wave_sum(dv);
    if (tid == 0) atomicAdd(&Dacc[j], dsum);
  }
  __threadfence();
  if (tid == 0) lastflag = (atomicAdd(&jtick[j], 1) == 3);
  __syncthreads();
  if (!lastflag) return;

  // ---- finalize row j (this block saw all 4 quarters complete) ----
  float tot = 0.0f;
  if (tid < 64) {
    float n = atomicAdd(&Cacc[j * DM + tid], 0.0f);
    float dn = atomicAdd(&Dacc[j], 0.0f);
    float cval = n / dn;
    Cnew[j * DM + tid] = cval;
    if (compute_diff) {
      float df = cval - Cold[j * DM + tid];
      tot = wave_sum(df * df);
      if (tid == 0) atomicAdd(diffac, tot);
    }
    Cacc[j * DM + tid] = 0.0f;             // reset for next iteration
    if (tid == 0) { Dacc[j] = 0.0f; jtick[j] = 0; }
  }
  __threadfence();
  __syncthreads();
  if (tid == 0) lastflag = (atomicAdd(ticket, 1) == CL - 1);
  __syncthreads();
  if (!lastflag) return;

  // ---- convergence tail (last finalizer) ----
  if (tid == 0) sdv = atomicAdd(diffac, 0.0f);
  __syncthreads();
  if (compute_diff && sdv < 1e-16f) {      // diff < 1e-8  <=>  diff^2 < 1e-16
    for (int i = tid; i < CL * DM; i += 256) out[i] = Cold[i];
    if (tid == 0) *done = 1;
  }
  if (tid == 0) { *diffac = 0.0f; *ticket = 0; }
}

// If never converged, V = C_25.
__global__ void fcm_final(const float* __restrict__ Clast, float* __restrict__ out,
                          const int* __restrict__ done) {
  if (*done) return;
  int i = blockIdx.x * blockDim.x + threadIdx.x;
  if (i < CL * DM) out[i] = Clast[i];
}

extern "C" void kernel_launch(void* const* d_in, const int* in_sizes, int n_in,
                              void* d_out, int out_size, void* d_ws, size_t ws_size,
                              hipStream_t stream) {
  const float* data = (const float*)d_in[0];
  const float* u0   = (const float*)d_in[1];
  float* out = (float*)d_out;
  int N = in_sizes[0] / DM;            // 300000
  int ntiles = (N + 63) / 64;          // 4688

  float* ws = (float*)d_ws;
  size_t Noff = ((size_t)N + 15) & ~(size_t)15;
  float* x2 = ws;                                  // N fp32
  unsigned short* xbf = (unsigned short*)(ws + Noff);  // N*64 bf16 = N*32 float slots
  float* C0 = ws + Noff + (size_t)N * 32;
  float* C1 = C0 + CL * DM;
  float* diffac = C1 + CL * DM;
  int* done = (int*)(diffac + 1);
  int* ticket = (int*)(diffac + 2);
  float* zacc = diffac + 16;                       // Cacc 4096 | Dacc 64 | jtick 64
  float* Cacc = zacc;
  float* Dacc = zacc + CL * DM;
  int* jtick = (int*)(zacc + CL * DM + CL);
  float* partial = zacc + ZACC_SZ;

  size_t used = Noff + (size_t)N * 32 + 2 * CL * DM + 16 + ZACC_SZ;
  size_t avail = (ws_size / 4 > used) ? (ws_size / 4 - used) / PARTIAL_STRIDE : 0;
  int nb = (int)(avail < MAX_BLOCKS ? avail : MAX_BLOCKS);
  if (nb < 4) nb = 4;

  size_t nvec = (size_t)N * (DM / 4);
  hipLaunchKernelGGL(fcm_prep, dim3((unsigned)((nvec + 255) / 256)), dim3(256), 0,
                     stream, data, x2, xbf, zacc, diffac, done, ticket, N);
  hipLaunchKernelGGL((fcm_pass<true>), dim3(nb), dim3(256), 0, stream,
                     xbf, x2, u0, partial, done, N, ntiles);
  hipLaunchKernelGGL(fcm_reduce, dim3(256), dim3(256), 0, stream,
                     partial, C0, C1, out, Cacc, Dacc, jtick,
                     diffac, done, ticket, 0, nb);

  float* bufs[2] = {C0, C1};
  for (int k = 0; k < MAX_ITER; k++) {
    float* Cc = bufs[k & 1];
    float* Cn = bufs[(k + 1) & 1];
    hipLaunchKernelGGL((fcm_pass<false>), dim3(nb), dim3(256), 0, stream,
                       xbf, x2, Cc, partial, done, N, ntiles);
    hipLaunchKernelGGL(fcm_reduce, dim3(256), dim3(256), 0, stream,
                       partial, Cn, Cc, out, Cacc, Dacc, jtick,
                       diffac, done, ticket, 1, nb);
  }
  hipLaunchKernelGGL(fcm_final, dim3(16), dim3(256), 0, stream,
                     bufs[1], out, done);
}

// Round 5
// 379.022 us; speedup vs baseline: 1.2389x; 1.2389x over previous
//
#include <hip/hip_runtime.h>

// Fuzzy c-means on MI355X. N=300000, D=64, c=64, m=2 (p=2), 25 updates + init.
// R4: MFMA rewrite (432us). R5: bf16 xbf copy (427us). R6: VALU cuts (401us).
// R7: coalesced prep, nb=768 (390us). R8: per-wave-points GEMM1 (388us).
// R9: pipelined pass (GEMM2 deferred a tile, 2 barriers/tile, reg prefetch)
//     was a WIN (pass 53.7 -> <46us profiled) but the 256x256 atomic-staged
//     reduce was a big LOSS (46us profiled, 206GB/s, 4 waves/CU) -> 470us.
// R10: keep R9 pass, revert reduce to the proven R8 64x1024 structure
//     (16 waves/CU -> enough MLP), drop zacc machinery.

#define DM 64
#define CL 64
#define PARTIAL_STRIDE 4160      // 64*64 num + 64 den
#define MAX_ITER 25
#define MAX_BLOCKS 768
#define LDP 72                   // padded row length (bf16) for Xb/XTb/umT

typedef __attribute__((ext_vector_type(8))) short bf16x8;   // MFMA A/B frag (4 VGPRs)
typedef __attribute__((ext_vector_type(4))) float f32x4;    // MFMA C/D frag

__device__ __forceinline__ unsigned f2bf1(float f) {        // fp32 -> bf16 (RNE)
  unsigned u = __builtin_bit_cast(unsigned, f);
  return (u + 0x7FFFu + ((u >> 16) & 1u)) >> 16;
}
__device__ __forceinline__ unsigned pkbf(float a, float b) {
  return f2bf1(a) | (f2bf1(b) << 16);
}
// HW packed fp32->2xbf16 (RNE), gfx950. %1 -> low half, %2 -> high half.
__device__ __forceinline__ unsigned cvtpk_bf16(float a, float b) {
  unsigned r;
  asm("v_cvt_pk_bf16_f32 %0, %1, %2" : "=v"(r) : "v"(a), "v"(b));
  return r;
}

// 64-lane sum: DPP row reduce + bcast, result broadcast via readlane 63.
__device__ __forceinline__ float wave_sum(float v) {
#define DPPADD(ctrl, rmask)                                                  \
  v += __builtin_bit_cast(float, __builtin_amdgcn_update_dpp(                \
           0, __builtin_bit_cast(int, v), ctrl, rmask, 0xf, false));
  DPPADD(0x111, 0xf)   // row_shr:1
  DPPADD(0x112, 0xf)   // row_shr:2
  DPPADD(0x114, 0xf)   // row_shr:4
  DPPADD(0x118, 0xf)   // row_shr:8
  DPPADD(0x142, 0xa)   // row_bcast:15
  DPPADD(0x143, 0xc)   // row_bcast:31
#undef DPPADD
  return __builtin_bit_cast(
      float, __builtin_amdgcn_readlane(__builtin_bit_cast(int, v), 63));
}

// all-lanes sum within each 16-lane group, pure VALU (DPP).
__device__ __forceinline__ float group16_sum(float v) {
#define DPPADD(ctrl)                                                         \
  v += __builtin_bit_cast(float, __builtin_amdgcn_update_dpp(                \
           0, __builtin_bit_cast(int, v), ctrl, 0xf, 0xf, false));
  DPPADD(0xB1)    // quad_perm [1,0,3,2]  (xor 1)
  DPPADD(0x4E)    // quad_perm [2,3,0,1]  (xor 2)
  DPPADD(0x141)   // row_half_mirror
  DPPADD(0x140)   // row_mirror
#undef DPPADD
  return v;
}

// Coalesced prep: one float4 per lane, 16 lanes = one data row.
// x2[i] = ||x_i||^2 via DPP 16-lane sum; bf16 copy via hw cvt_pk; flag reset.
__global__ __launch_bounds__(256)
void fcm_prep(const float* __restrict__ data, float* __restrict__ x2,
              unsigned short* __restrict__ xbf,
              float* __restrict__ diffac, int* __restrict__ done,
              int* __restrict__ ticket, int N) {
  size_t i = (size_t)blockIdx.x * blockDim.x + threadIdx.x;   // float4 index
  if (i == 0) { *diffac = 0.0f; *done = 0; *ticket = 0; }
  size_t nvec = (size_t)N * (DM / 4);
  if (i >= nvec) return;                 // rows are 16 vecs: groups all-in/all-out
  float4 v = ((const float4*)data)[i];
  float s = fmaf(v.x, v.x, fmaf(v.y, v.y, fmaf(v.z, v.z, v.w * v.w)));
  float rs = group16_sum(s);             // row sum across the 16-lane group
  if ((threadIdx.x & 15) == 0) x2[i >> 4] = rs;
  uint2 pk = {cvtpk_bf16(v.x, v.y), cvtpk_bf16(v.z, v.w)};
  ((uint2*)xbf)[i] = pk;
}

// Fused pass, software-pipelined:
//   iter i: barA; [GEMM2(prev tile) || stage regs->buf c]; issue loads(i+1);
//           barB; GEMM1+softmax+umT(buf c).  Final GEMM2 drained after loop.
template <bool INIT>
__global__ __launch_bounds__(256, 3)
void fcm_pass(const unsigned short* __restrict__ xbf, const float* __restrict__ x2,
              const float* __restrict__ CU,   // INIT: u0[N][64]; else C[64][64]
              float* __restrict__ partial, const int* __restrict__ done,
              int N, int ntiles) {
  if (!INIT && *done) return;
  __shared__ __align__(16) unsigned short Xb[2][64 * LDP];   // X[p][d] bf16
  __shared__ __align__(16) unsigned short XTb[2][64 * LDP];  // X^T[d][p] bf16
  __shared__ __align__(16) unsigned short umT[64 * LDP];     // um^T[j][p] bf16
  __shared__ __align__(16) float x2s[2][64];

  const int tid  = threadIdx.x;
  const int w    = __builtin_amdgcn_readfirstlane(tid >> 6);  // wave id: POINT tile
  const int col  = tid & 15;
  const int quad = (tid >> 4) & 3;

  // ---- per-kernel prep: ALL 4 j-tiles' C rows -> c2v[jt] + bf16 B-frags ----
  bf16x8 cf0[4], cf1[4];
  float c2v[4];
  if (!INIT) {
#pragma unroll
    for (int jt = 0; jt < 4; jt++) {
      const float* crow = CU + (size_t)(16 * jt + col) * DM;
      float4 ca = *(const float4*)(crow + quad * 8);
      float4 cb = *(const float4*)(crow + quad * 8 + 4);
      float4 cc = *(const float4*)(crow + 32 + quad * 8);
      float4 cd = *(const float4*)(crow + 32 + quad * 8 + 4);
      float cp = ca.x*ca.x + ca.y*ca.y + ca.z*ca.z + ca.w*ca.w
               + cb.x*cb.x + cb.y*cb.y + cb.z*cb.z + cb.w*cb.w
               + cc.x*cc.x + cc.y*cc.y + cc.z*cc.z + cc.w*cc.w
               + cd.x*cd.x + cd.y*cd.y + cd.z*cd.z + cd.w*cd.w;
      cp += __shfl_xor(cp, 16, 64);
      cp += __shfl_xor(cp, 32, 64);
      c2v[jt] = cp;
      union { bf16x8 v; unsigned u[4]; } P0, P1;
      P0.u[0] = pkbf(ca.x, ca.y); P0.u[1] = pkbf(ca.z, ca.w);
      P0.u[2] = pkbf(cb.x, cb.y); P0.u[3] = pkbf(cb.z, cb.w);
      P1.u[0] = pkbf(cc.x, cc.y); P1.u[1] = pkbf(cc.z, cc.w);
      P1.u[2] = pkbf(cd.x, cd.y); P1.u[3] = pkbf(cd.z, cd.w);
      cf0[jt] = P0.v; cf1[jt] = P1.v;
    }
  }

  union { bf16x8 v; unsigned u[4]; } ON;
  ON.u[0] = ON.u[1] = ON.u[2] = ON.u[3] = 0x3F803F80u;   // bf16 1.0 x2
  const bf16x8 onesf = ON.v;

  f32x4 D2[4];
#pragma unroll
  for (int dt = 0; dt < 4; dt++) D2[dt] = f32x4{0.f, 0.f, 0.f, 0.f};
  f32x4 Dden = f32x4{0.f, 0.f, 0.f, 0.f};

  const int sp  = tid & 63;
  const int sd0 = (tid >> 6) * 8;                         // 0/8/16/24 by wave
  const unsigned short* gsrc = xbf + (size_t)sp * DM + sd0;

  // deferred GEMM2 over buffer cb (reads umT + XTb[cb], accumulates D2/Dden)
  auto do_gemm2 = [&](int cb) {
#pragma unroll
    for (int pb = 0; pb < 2; pb++) {
      bf16x8 au = *(const bf16x8*)(const void*)&umT[(16 * w + col) * LDP + pb * 32 + quad * 8];
      Dden = __builtin_amdgcn_mfma_f32_16x16x32_bf16(au, onesf, Dden, 0, 0, 0);
#pragma unroll
      for (int dt = 0; dt < 4; dt++) {
        bf16x8 bx = *(const bf16x8*)(const void*)&XTb[cb][(dt * 16 + col) * LDP + pb * 32 + quad * 8];
        D2[dt] = __builtin_amdgcn_mfma_f32_16x16x32_bf16(au, bx, D2[dt], 0, 0, 0);
      }
    }
  };

  // ---- prologue prefetch: tile #0 for this block ----
  bf16x8 rv0 = {0, 0, 0, 0, 0, 0, 0, 0};
  bf16x8 rv1 = {0, 0, 0, 0, 0, 0, 0, 0};
  float rx2 = 0.0f;
  {
    int t0 = blockIdx.x;
    if (t0 < ntiles) {
      int base = t0 * 64;
      int np = min(64, N - base);
      if (sp < np) {
        const unsigned short* g = gsrc + (size_t)base * DM;
        rv0 = *(const bf16x8*)(g);
        rv1 = *(const bf16x8*)(g + 32);
      }
      if (tid < 64 && base + tid < N) rx2 = x2[base + tid];
    }
  }

  int c = 0;
  int it = 0;
  for (int t = blockIdx.x; t < ntiles; t += gridDim.x, ++it) {
    const int base = t * 64;
    const int np = min(64, N - base);
    __syncthreads();                       // barA: prev compute done everywhere

    if (it > 0) do_gemm2(c ^ 1);           // finish previous tile (other buffer)

    // ---- stage prefetched regs -> buf c ----
    *(bf16x8*)(void*)&Xb[c][sp * LDP + sd0] = rv0;
    *(bf16x8*)(void*)&Xb[c][sp * LDP + sd0 + 32] = rv1;
#pragma unroll
    for (int k = 0; k < 8; k++) XTb[c][(sd0 + k) * LDP + sp] = (unsigned short)rv0[k];
#pragma unroll
    for (int k = 0; k < 8; k++) XTb[c][(sd0 + 32 + k) * LDP + sp] = (unsigned short)rv1[k];
    if (tid < 64) x2s[c][tid] = rx2;

    // ---- issue next tile's global loads (consumed next iteration) ----
    {
      int tn = t + gridDim.x;
      rv0 = bf16x8{0, 0, 0, 0, 0, 0, 0, 0};
      rv1 = bf16x8{0, 0, 0, 0, 0, 0, 0, 0};
      rx2 = 0.0f;
      if (tn < ntiles) {
        int nbase = tn * 64;
        int nnp = min(64, N - nbase);
        if (sp < nnp) {
          const unsigned short* g = gsrc + (size_t)nbase * DM;
          rv0 = *(const bf16x8*)(g);
          rv1 = *(const bf16x8*)(g + 32);
        }
        if (tid < 64 && nbase + tid < N) rx2 = x2[nbase + tid];
      }
    }
    __syncthreads();                       // barB: stage(c) done, umT free

    // ---- W[jt][r] for p = 16w+quad*4+r, j = 16jt+col ----
    float Wv[4][4];
    if (INIT) {
#pragma unroll
      for (int jt = 0; jt < 4; jt++)
#pragma unroll
        for (int r = 0; r < 4; r++) {
          int pl = 16 * w + quad * 4 + r;
          Wv[jt][r] = (pl < np)
              ? CU[(size_t)(base + pl) * CL + 16 * jt + col] : 0.0f;
        }
    } else {
      bf16x8 a0 = *(const bf16x8*)(const void*)&Xb[c][(16 * w + col) * LDP + quad * 8];
      bf16x8 a1 = *(const bf16x8*)(const void*)&Xb[c][(16 * w + col) * LDP + 32 + quad * 8];
      f32x4 x2p = *(const f32x4*)(const void*)&x2s[c][16 * w + quad * 4];
#pragma unroll
      for (int jt = 0; jt < 4; jt++) {
        f32x4 s = f32x4{0.f, 0.f, 0.f, 0.f};
        s = __builtin_amdgcn_mfma_f32_16x16x32_bf16(a0, cf0[jt], s, 0, 0, 0);
        s = __builtin_amdgcn_mfma_f32_16x16x32_bf16(a1, cf1[jt], s, 0, 0, 0);
#pragma unroll
        for (int r = 0; r < 4; r++) {
          float dist = fmaxf(fmaf(-2.0f, s[r], x2p[r] + c2v[jt]), 0.0f);
          Wv[jt][r] = __builtin_amdgcn_rcpf(dist);   // d^(-p/2), p=2
        }
      }
    }

    // ---- rowsum in-register: in-lane over jt, DPP over col (bcast in group) ----
    float rr[4];
#pragma unroll
    for (int r = 0; r < 4; r++) {
      float rs = Wv[0][r] + Wv[1][r] + Wv[2][r] + Wv[3][r];
      rs = group16_sum(rs);
      int pl = 16 * w + quad * 4 + r;
      rr[r] = (pl < np) ? __builtin_amdgcn_rcpf(rs) : 0.0f;
    }

    // ---- um = (W * rr)^2 -> bf16 umT write (hw cvt_pk) ----
#pragma unroll
    for (int jt = 0; jt < 4; jt++) {
      float u0v = Wv[jt][0] * rr[0], u1v = Wv[jt][1] * rr[1];
      float u2v = Wv[jt][2] * rr[2], u3v = Wv[jt][3] * rr[3];
      uint2 pk = {cvtpk_bf16(u0v * u0v, u1v * u1v),
                  cvtpk_bf16(u2v * u2v, u3v * u3v)};
      *(uint2*)(void*)&umT[(16 * jt + col) * LDP + 16 * w + quad * 4] = pk;
    }
    c ^= 1;
  }

  // ---- drain: last tile's GEMM2 ----
  if (it > 0) {
    __syncthreads();
    do_gemm2(c ^ 1);
  }

  // ---- epilogue: write per-block partial (den from MFMA, col-duplicated) ----
  float* pbuf = partial + (size_t)blockIdx.x * PARTIAL_STRIDE;
  if (col == 0) {
    float4 dv = {Dden[0], Dden[1], Dden[2], Dden[3]};
    *(float4*)(void*)&pbuf[CL * DM + 16 * w + quad * 4] = dv;
  }
#pragma unroll
  for (int dt = 0; dt < 4; dt++)
#pragma unroll
    for (int r = 0; r < 4; r++)
      pbuf[(size_t)(16 * w + quad * 4 + r) * DM + dt * 16 + col] = D2[dt][r];
}

// Sum partials -> C_new; Frobenius diff; last block (ticket) does convergence
// check. R8-proven structure: 64 blocks x 1024 threads (16 waves/CU -> MLP).
__global__ __launch_bounds__(1024, 1)
void fcm_reduce(const float* __restrict__ partial, float* __restrict__ Cnew,
                const float* __restrict__ Cold, float* __restrict__ out,
                float* __restrict__ diffac, int* __restrict__ done,
                int* __restrict__ ticket, int compute_diff, int nb) {
  if (compute_diff && *done) return;
  __shared__ float sm[16 * 64];
  __shared__ float sden[1024];
  __shared__ int lastflag;
  __shared__ float sdiff;
  int j = blockIdx.x;
  int tid = threadIdx.x;
  int d = tid & 63;
  int slice = tid >> 6;
  float s = 0.0f;
  for (int b = slice; b < nb; b += 16)
    s += partial[(size_t)b * PARTIAL_STRIDE + j * DM + d];
  sm[slice * 64 + d] = s;
  float dv = 0.0f;
  for (int b = tid; b < nb; b += 1024)
    dv += partial[(size_t)b * PARTIAL_STRIDE + CL * DM + j];
  sden[tid] = dv;
  __syncthreads();
#pragma unroll
  for (int st = 8; st; st >>= 1) {
    if (slice < st) sm[slice * 64 + d] += sm[(slice + st) * 64 + d];
    __syncthreads();
  }
#pragma unroll
  for (int st = 512; st >= 64; st >>= 1) {
    if (tid < st) sden[tid] += sden[tid + st];
    __syncthreads();
  }
  if (tid < 64) {
    float denj = wave_sum(sden[tid]);
    float c = sm[tid] / denj;
    Cnew[j * DM + tid] = c;
    if (compute_diff) {
      float df = c - Cold[j * DM + tid];
      float tot = wave_sum(df * df);
      if (tid == 0) atomicAdd(diffac, tot);
    }
  }
  if (!compute_diff) return;
  __syncthreads();
  if (tid == 0) {
    __threadfence();
    int t = atomicAdd(ticket, 1);
    lastflag = (t == (int)gridDim.x - 1);
  }
  __syncthreads();
  if (!lastflag) return;
  if (tid == 0) sdiff = atomicAdd(diffac, 0.0f);
  __syncthreads();
  if (sdiff < 1e-16f) {                 // diff < 1e-8  <=>  diff^2 < 1e-16
    for (int i = tid; i < CL * DM; i += 1024) out[i] = Cold[i];
    if (tid == 0) *done = 1;
  }
  if (tid == 0) { *diffac = 0.0f; *ticket = 0; }
}

// If never converged, V = C_25.
__global__ void fcm_final(const float* __restrict__ Clast, float* __restrict__ out,
                          const int* __restrict__ done) {
  if (*done) return;
  int i = blockIdx.x * blockDim.x + threadIdx.x;
  if (i < CL * DM) out[i] = Clast[i];
}

extern "C" void kernel_launch(void* const* d_in, const int* in_sizes, int n_in,
                              void* d_out, int out_size, void* d_ws, size_t ws_size,
                              hipStream_t stream) {
  const float* data = (const float*)d_in[0];
  const float* u0   = (const float*)d_in[1];
  float* out = (float*)d_out;
  int N = in_sizes[0] / DM;            // 300000
  int ntiles = (N + 63) / 64;          // 4688

  float* ws = (float*)d_ws;
  size_t Noff = ((size_t)N + 15) & ~(size_t)15;
  float* x2 = ws;                                  // N fp32
  unsigned short* xbf = (unsigned short*)(ws + Noff);  // N*64 bf16 = N*32 float slots
  float* C0 = ws + Noff + (size_t)N * 32;
  float* C1 = C0 + CL * DM;
  float* diffac = C1 + CL * DM;
  int* done = (int*)(diffac + 1);
  int* ticket = (int*)(diffac + 2);
  float* partial = diffac + 16;

  size_t used = Noff + (size_t)N * 32 + 2 * CL * DM + 16;
  size_t avail = (ws_size / 4 > used) ? (ws_size / 4 - used) / PARTIAL_STRIDE : 0;
  int nb = (int)(avail < MAX_BLOCKS ? avail : MAX_BLOCKS);
  if (nb < 1) nb = 1;

  size_t nvec = (size_t)N * (DM / 4);
  hipLaunchKernelGGL(fcm_prep, dim3((unsigned)((nvec + 255) / 256)), dim3(256), 0,
                     stream, data, x2, xbf, diffac, done, ticket, N);
  hipLaunchKernelGGL((fcm_pass<true>), dim3(nb), dim3(256), 0, stream,
                     xbf, x2, u0, partial, done, N, ntiles);
  hipLaunchKernelGGL(fcm_reduce, dim3(64), dim3(1024), 0, stream,
                     partial, C0, C1, out, diffac, done, ticket, 0, nb);

  float* bufs[2] = {C0, C1};
  for (int k = 0; k < MAX_ITER; k++) {
    float* Cc = bufs[k & 1];
    float* Cn = bufs[(k + 1) & 1];
    hipLaunchKernelGGL((fcm_pass<false>), dim3(nb), dim3(256), 0, stream,
                       xbf, x2, Cc, partial, done, N, ntiles);
    hipLaunchKernelGGL(fcm_reduce, dim3(64), dim3(1024), 0, stream,
                       partial, Cn, Cc, out, diffac, done, ticket, 1, nb);
  }
  hipLaunchKernelGGL(fcm_final, dim3(16), dim3(256), 0, stream,
                     bufs[1], out, done);
}